// Round 1
// baseline (285.197 us; speedup 1.0000x reference)
//
#include <hip/hip_runtime.h>
#include <hip/hip_bf16.h>

typedef unsigned int u32;
typedef unsigned short u16;
typedef __attribute__((ext_vector_type(8))) __bf16 bf16x8;
typedef __attribute__((ext_vector_type(16))) float f32x16;

// log2(e) / sqrt(32): folds softmax's exp->exp2 conversion and the 1/sqrt(rank)
// score scale into the Q projection.
#define QSCALE 0.25505418f

static __device__ __forceinline__ u16 f2b(float f) {
  __hip_bfloat16 h = __float2bfloat16(f);
  return *reinterpret_cast<u16*>(&h);
}
static __device__ __forceinline__ u32 pk2(float lo, float hi2) {
  return (u32)f2b(lo) | ((u32)f2b(hi2) << 16);
}

// ---------------------------------------------------------------------------
// K1: fold per-head weight matrices.
//   WQ/WK/WV[h][rp][r] = sum_d qkv_v[rp, off+h*64+d] * u_attn[h,d,r]
//   WO[h][r][r2]       = sum_d v_attn[h,r,d] * out_u[h*64+d, r2]
//   BQKV: bq|bk|bv[h][r] = sum_d qkv_b[off+h*64+d] * u_attn[h,d,r]
// ---------------------------------------------------------------------------
__global__ __launch_bounds__(256) void k_prep(const float* __restrict__ qkv_v,
                                              const float* __restrict__ qkv_b,
                                              const float* __restrict__ u_attn,
                                              const float* __restrict__ v_attn,
                                              const float* __restrict__ out_u,
                                              float* __restrict__ WQ, float* __restrict__ WK,
                                              float* __restrict__ WV, float* __restrict__ BQKV,
                                              float* __restrict__ WO) {
  int h = blockIdx.x;
  int r = threadIdx.x & 31, g = threadIdx.x >> 5;
  for (int rp = g; rp < 32; rp += 8) {
    float aq = 0.f, ak = 0.f, av = 0.f;
    for (int d = 0; d < 64; ++d) {
      float u = u_attn[(h * 64 + d) * 32 + r];
      aq += qkv_v[rp * 3072 + h * 64 + d] * u;
      ak += qkv_v[rp * 3072 + 1024 + h * 64 + d] * u;
      av += qkv_v[rp * 3072 + 2048 + h * 64 + d] * u;
    }
    WQ[h * 1024 + rp * 32 + r] = aq;
    WK[h * 1024 + rp * 32 + r] = ak;
    WV[h * 1024 + rp * 32 + r] = av;
  }
  for (int rr = g; rr < 32; rr += 8) {
    float a = 0.f;
    for (int d = 0; d < 64; ++d)
      a += v_attn[(h * 32 + rr) * 64 + d] * out_u[(h * 64 + d) * 32 + r];
    WO[(h * 32 + rr) * 32 + r] = a;
  }
  if (threadIdx.x < 32) {
    float aq = 0.f, ak = 0.f, av = 0.f;
    for (int d = 0; d < 64; ++d) {
      float u = u_attn[(h * 64 + d) * 32 + r];
      aq += qkv_b[h * 64 + d] * u;
      ak += qkv_b[1024 + h * 64 + d] * u;
      av += qkv_b[2048 + h * 64 + d] * u;
    }
    BQKV[h * 32 + r] = aq;
    BQKV[512 + h * 32 + r] = ak;
    BQKV[1024 + h * 32 + r] = av;
  }
}

// ---------------------------------------------------------------------------
// K2: t = x @ qkv_u   [8192 x 1024] @ [1024 x 32] -> [8192 x 32] f32
// thread (g=row-in-block, r=output col); x row loads are float4 broadcast.
// ---------------------------------------------------------------------------
__global__ __launch_bounds__(256) void k_proj_t(const float* __restrict__ x,
                                                const float* __restrict__ qkv_u,
                                                float* __restrict__ T) {
  int g = threadIdx.x >> 5, r = threadIdx.x & 31;
  size_t row = (size_t)blockIdx.x * 8 + g;
  const float* xr = x + row * 1024;
  float acc = 0.f;
  for (int k = 0; k < 1024; k += 4) {
    float4 xv = *(const float4*)(xr + k);
    acc += xv.x * qkv_u[(k + 0) * 32 + r];
    acc += xv.y * qkv_u[(k + 1) * 32 + r];
    acc += xv.z * qkv_u[(k + 2) * 32 + r];
    acc += xv.w * qkv_u[(k + 3) * 32 + r];
  }
  T[row * 32 + r] = acc;
}

// ---------------------------------------------------------------------------
// K3: per-head low-rank Q/K/V.
//   QL[bh][s][r] = (t@WQ[h] + bq)*QSCALE (bf16), KL likewise (unscaled),
//   VT[bh][r][s] = (t@WV[h] + bv)      (bf16, TRANSPOSED for PV A-fragment)
// grid: (bh, sblock of 64 rows)
// ---------------------------------------------------------------------------
__global__ __launch_bounds__(256) void k_lowproj(const float* __restrict__ T,
                                                 const float* __restrict__ WQ,
                                                 const float* __restrict__ WK,
                                                 const float* __restrict__ WV,
                                                 const float* __restrict__ BQKV,
                                                 u16* __restrict__ QL, u16* __restrict__ KL,
                                                 u16* __restrict__ VT) {
  __shared__ float tl[64][33];
  __shared__ u16 vt[32][68];
  int blk = blockIdx.x;
  int bh = blk >> 5, sblock = blk & 31;
  int b = bh >> 4, h = bh & 15;
  int sbase = sblock * 64;
  int tid = threadIdx.x;
  int g = tid >> 5, r = tid & 31;
  for (int j = 0; j < 8; ++j) {
    int srow = g + 8 * j;
    tl[srow][r] = T[((size_t)(b * 2048 + sbase + srow)) * 32 + r];
  }
  __syncthreads();
  float bq = BQKV[h * 32 + r], bk = BQKV[512 + h * 32 + r], bv = BQKV[1024 + h * 32 + r];
  for (int j = 0; j < 8; ++j) {
    int srow = g + 8 * j;
    float aq = bq, ak = bk, av = bv;
    for (int rp = 0; rp < 32; ++rp) {
      float tt = tl[srow][rp];
      aq += tt * WQ[h * 1024 + rp * 32 + r];
      ak += tt * WK[h * 1024 + rp * 32 + r];
      av += tt * WV[h * 1024 + rp * 32 + r];
    }
    size_t sg = (size_t)bh * 2048 + sbase + srow;
    QL[sg * 32 + r] = f2b(aq * QSCALE);
    KL[sg * 32 + r] = f2b(ak);
    vt[r][srow] = f2b(av);
  }
  __syncthreads();
  int rr = tid >> 3, c0 = (tid & 7) * 8;
  ushort4 w0 = *(ushort4*)&vt[rr][c0];
  ushort4 w1 = *(ushort4*)&vt[rr][c0 + 4];
  size_t base = ((size_t)bh * 32 + rr) * 2048 + sbase + c0;
  *(ushort4*)(VT + base) = w0;
  *(ushort4*)(VT + base + 4) = w1;
}

// ---------------------------------------------------------------------------
// K4: flash attention, swapped-operand 32x32x16 bf16 MFMA.
// One wave owns 32 q-columns; per 32-key tile:
//   S^T = mfma(K_frag, Q^T_frag) twice (rank 32 = 2 k-steps)
//   online softmax: lane holds 16 scores of one q -> 1 shfl_xor(32) reduce
//   P packed to bf16 in-reg, half-wave exchange via shfl_xor(32),
//   ctx^T accumulated by mfma(VT_frag, P_frag).
// D layout (guide-verified): col = lane&31, row = (reg&3)+8*(reg>>2)+4*(lane>>5)
// ---------------------------------------------------------------------------
__global__ __launch_bounds__(256) void k_attn(const u16* __restrict__ QL,
                                              const u16* __restrict__ KL,
                                              const u16* __restrict__ VT,
                                              const int* __restrict__ mask,
                                              float* __restrict__ CT) {
  int tid = threadIdx.x;
  int wave = tid >> 6;
  int l = tid & 63;
  int lo = l & 31;
  int hi = l >> 5;
  int blk = blockIdx.x;
  int bh = blk >> 4;
  int qt = (blk & 15) * 4 + wave;  // 0..63
  int b = bh >> 4;

  const u16* QLbh = QL + (size_t)bh * 2048 * 32;
  const u16* KLbh = KL + (size_t)bh * 2048 * 32;
  const u16* VTbh = VT + (size_t)bh * 32 * 2048;
  const int* mk = mask + b * 2048;

  int q = qt * 32 + lo;
  bf16x8 qb0 = *(const bf16x8*)(QLbh + q * 32 + hi * 8);
  bf16x8 qb1 = *(const bf16x8*)(QLbh + q * 32 + 16 + hi * 8);

  f32x16 acc = {};
  float m_run = -3.0e38f, l_run = 0.f;

  for (int kt = 0; kt < 64; ++kt) {
    int kb = kt * 32;
    int mval = mk[kb + lo];
    unsigned long long bm = __ballot(mval != 0);
    const u16* kp = KLbh + (size_t)(kb + lo) * 32 + hi * 8;
    bf16x8 ka0 = *(const bf16x8*)(kp);
    bf16x8 ka1 = *(const bf16x8*)(kp + 16);
    f32x16 sc = {};
    sc = __builtin_amdgcn_mfma_f32_32x32x16_bf16(ka0, qb0, sc, 0, 0, 0);
    sc = __builtin_amdgcn_mfma_f32_32x32x16_bf16(ka1, qb1, sc, 0, 0, 0);
    if (~bm) {  // rare: some key masked
      u32 km = (u32)bm;
#pragma unroll
      for (int i = 0; i < 16; ++i) {
        int key = (i & 3) + 8 * (i >> 2) + 4 * hi;
        if (!((km >> key) & 1)) sc[i] = -3.0e38f;
      }
    }
    float mx = sc[0];
#pragma unroll
    for (int i = 1; i < 16; ++i) mx = fmaxf(mx, sc[i]);
    mx = fmaxf(mx, __shfl_xor(mx, 32));
    float mn = fmaxf(m_run, mx);
    float alpha = __builtin_amdgcn_exp2f(m_run - mn);
    m_run = mn;
    float p[16];
    float ps = 0.f;
#pragma unroll
    for (int i = 0; i < 16; ++i) {
      p[i] = __builtin_amdgcn_exp2f(sc[i] - mn);
      ps += p[i];
    }
    ps += __shfl_xor(ps, 32);
    l_run = l_run * alpha + ps;
#pragma unroll
    for (int i = 0; i < 16; ++i) acc[i] *= alpha;
#pragma unroll
    for (int c = 0; c < 2; ++c) {
      // own key pairs for this 16-key chunk (keys relative to chunk, hi=0 lane):
      // W0={0,1} W1={2,3} W2={8,9} W3={10,11}; hi=1 lane holds +4.
      u32 W0 = pk2(p[8 * c + 0], p[8 * c + 1]);
      u32 W1 = pk2(p[8 * c + 2], p[8 * c + 3]);
      u32 W2 = pk2(p[8 * c + 4], p[8 * c + 5]);
      u32 W3 = pk2(p[8 * c + 6], p[8 * c + 7]);
      u32 pW0 = __shfl_xor(W0, 32);
      u32 pW1 = __shfl_xor(W1, 32);
      u32 pW2 = __shfl_xor(W2, 32);
      u32 pW3 = __shfl_xor(W3, 32);
      union { bf16x8 v; u32 u[4]; } fb;
      fb.u[0] = hi ? pW2 : W0;   // keys {8*hi+0, 8*hi+1}
      fb.u[1] = hi ? pW3 : W1;   // keys {8*hi+2, 8*hi+3}
      fb.u[2] = hi ? W2 : pW0;   // keys {8*hi+4, 8*hi+5}
      fb.u[3] = hi ? W3 : pW1;   // keys {8*hi+6, 8*hi+7}
      bf16x8 va = *(const bf16x8*)(VTbh + (size_t)lo * 2048 + kb + c * 16 + hi * 8);
      acc = __builtin_amdgcn_mfma_f32_32x32x16_bf16(va, fb.v, acc, 0, 0, 0);
    }
  }
  float inv = 1.0f / l_run;
#pragma unroll
  for (int i = 0; i < 16; ++i) {
    int r = (i & 3) + 8 * (i >> 2) + 4 * hi;
    CT[((size_t)bh * 32 + r) * 2048 + qt * 32 + lo] = acc[i] * inv;
  }
}

// ---------------------------------------------------------------------------
// K5: out[row,:] = (sum_{h,r} ctx^T[bh,r,row_s] * WO[hr,:]) @ out_v + out_b
// phase 1: 8 rows/block, lane = r2; phase 2: expand 32 -> 1024 via out_v.
// ---------------------------------------------------------------------------
__global__ __launch_bounds__(256) void k_epi(const float* __restrict__ CT,
                                             const float* __restrict__ WO,
                                             const float* __restrict__ out_v,
                                             const float* __restrict__ out_b,
                                             float* __restrict__ out) {
  __shared__ float accL[8][32];
  int tid = threadIdx.x;
  int g = tid >> 5, r2 = tid & 31;
  size_t row = (size_t)blockIdx.x * 8 + g;
  int b = (int)(row >> 11);
  int s = (int)(row & 2047);
  const float* cb = CT + (size_t)b * 512 * 2048 + s;
  float a = 0.f;
  for (int hr = 0; hr < 512; ++hr)
    a += cb[(size_t)hr * 2048] * WO[hr * 32 + r2];
  accL[g][r2] = a;
  __syncthreads();
  int lane = tid & 31;
  float ac[32];
#pragma unroll
  for (int i = 0; i < 32; ++i) ac[i] = accL[g][i];
  float* op = out + row * 1024;
  for (int pp = 0; pp < 8; ++pp) {
    int d0 = pp * 128 + lane * 4;
    float4 o = *(const float4*)(out_b + d0);
    for (int r = 0; r < 32; ++r) {
      float4 v = *(const float4*)(out_v + r * 1024 + d0);
      o.x += ac[r] * v.x;
      o.y += ac[r] * v.y;
      o.z += ac[r] * v.z;
      o.w += ac[r] * v.w;
    }
    *(float4*)(op + d0) = o;
  }
}

extern "C" void kernel_launch(void* const* d_in, const int* in_sizes, int n_in,
                              void* d_out, int out_size, void* d_ws, size_t ws_size,
                              hipStream_t stream) {
  const float* x = (const float*)d_in[0];
  const int* mask = (const int*)d_in[1];
  const float* qkv_u = (const float*)d_in[2];
  const float* qkv_v = (const float*)d_in[3];
  const float* qkv_b = (const float*)d_in[4];
  const float* u_attn = (const float*)d_in[5];
  const float* v_attn = (const float*)d_in[6];
  const float* out_u = (const float*)d_in[7];
  const float* out_v = (const float*)d_in[8];
  const float* out_b = (const float*)d_in[9];
  float* out = (float*)d_out;

  char* w = (char*)d_ws;
  float* T = (float*)(w);                    // 1 MB
  float* WQ = (float*)(w + (1 << 20));       // 64 KB
  float* WK = WQ + 16384;                    // 64 KB
  float* WV = WK + 16384;                    // 64 KB
  float* BQ = WV + 16384;                    // 6 KB (bq|bk|bv)
  float* WO = BQ + 1536;                     // 64 KB
  u16* QL = (u16*)(w + (2 << 20));           // 8 MB bf16 [bh][s][32]
  u16* KL = (u16*)(w + (10 << 20));          // 8 MB bf16 [bh][s][32]
  u16* VT = (u16*)(w + (18 << 20));          // 8 MB bf16 [bh][32][s]
  float* CT = (float*)(w + (26 << 20));      // 16 MB f32 [bh][32][s]

  k_prep<<<16, 256, 0, stream>>>(qkv_v, qkv_b, u_attn, v_attn, out_u, WQ, WK, WV, BQ, WO);
  k_proj_t<<<1024, 256, 0, stream>>>(x, qkv_u, T);
  k_lowproj<<<2048, 256, 0, stream>>>(T, WQ, WK, WV, BQ, QL, KL, VT);
  k_attn<<<1024, 256, 0, stream>>>(QL, KL, VT, mask, CT);
  k_epi<<<1024, 256, 0, stream>>>(CT, WO, out_v, out_b, out);
}

// Round 2
// 164.210 us; speedup vs baseline: 1.7368x; 1.7368x over previous
//
#include <hip/hip_runtime.h>
#include <hip/hip_bf16.h>

typedef unsigned int u32;
typedef unsigned short u16;
typedef __attribute__((ext_vector_type(8))) __bf16 bf16x8;
typedef __attribute__((ext_vector_type(16))) float f32x16;
typedef __attribute__((ext_vector_type(2))) unsigned int u32x2;

// log2(e)/sqrt(32): folds exp->exp2 and 1/sqrt(rank) into Q.
#define QSCALE 0.25505418f
#define MFMA __builtin_amdgcn_mfma_f32_32x32x16_bf16

static __device__ __forceinline__ u16 f2b(float f) {
  __hip_bfloat16 h = __float2bfloat16(f);
  return *reinterpret_cast<u16*>(&h);
}
static __device__ __forceinline__ u32 pk2(float lo, float hi2) {
  return (u32)f2b(lo) | ((u32)f2b(hi2) << 16);
}

// Cross-half (lane ^ 32) reduce. With src==dst, ANY half-swap semantics of
// permlane32_swap yields {own, partner} across the two results -> safe.
static __device__ __forceinline__ float xhalf_max(float v) {
#if __has_builtin(__builtin_amdgcn_permlane32_swap)
  u32 a = __float_as_uint(v);
  u32x2 r = __builtin_amdgcn_permlane32_swap(a, a, false, false);
  return fmaxf(__uint_as_float(r[0]), __uint_as_float(r[1]));
#else
  return fmaxf(v, __shfl_xor(v, 32));
#endif
}
static __device__ __forceinline__ float xhalf_sum(float v) {
#if __has_builtin(__builtin_amdgcn_permlane32_swap)
  u32 a = __float_as_uint(v);
  u32x2 r = __builtin_amdgcn_permlane32_swap(a, a, false, false);
  return __uint_as_float(r[0]) + __uint_as_float(r[1]);
#else
  return v + __shfl_xor(v, 32);
#endif
}

// ---------------------------------------------------------------------------
// K1: fold weights. WQT/WKT/WVT[h][r][rp] (bf16, pre-transposed for A-frags),
// BQKV f32 (bq|bk|bv), WOT[r2][hr] bf16, UT[r][k]=qkv_u^T bf16,
// OVT[d][r]=out_v^T bf16.
// ---------------------------------------------------------------------------
__global__ __launch_bounds__(256) void k_prep(const float* __restrict__ qkv_v,
                                              const float* __restrict__ qkv_b,
                                              const float* __restrict__ u_attn,
                                              const float* __restrict__ v_attn,
                                              const float* __restrict__ out_u,
                                              const float* __restrict__ qkv_u,
                                              const float* __restrict__ out_v,
                                              u16* __restrict__ WQT, u16* __restrict__ WKT,
                                              u16* __restrict__ WVT, float* __restrict__ BQKV,
                                              u16* __restrict__ WOT, u16* __restrict__ UT,
                                              u16* __restrict__ OVT) {
  int blk = blockIdx.x;
  int tid = threadIdx.x;
  if (blk < 16) {
    int h = blk;
    int r = tid & 31, g = tid >> 5;
    for (int rp = g; rp < 32; rp += 8) {
      float aq = 0.f, ak = 0.f, av = 0.f;
      for (int d = 0; d < 64; ++d) {
        float u = u_attn[(h * 64 + d) * 32 + r];
        aq += qkv_v[rp * 3072 + h * 64 + d] * u;
        ak += qkv_v[rp * 3072 + 1024 + h * 64 + d] * u;
        av += qkv_v[rp * 3072 + 2048 + h * 64 + d] * u;
      }
      WQT[(h * 32 + r) * 32 + rp] = f2b(aq);
      WKT[(h * 32 + r) * 32 + rp] = f2b(ak);
      WVT[(h * 32 + r) * 32 + rp] = f2b(av);
    }
    for (int rr = g; rr < 32; rr += 8) {
      float a = 0.f;
      for (int d = 0; d < 64; ++d)
        a += v_attn[(h * 32 + rr) * 64 + d] * out_u[(h * 64 + d) * 32 + r];
      WOT[r * 512 + h * 32 + rr] = f2b(a);
    }
    if (tid < 32) {
      float aq = 0.f, ak = 0.f, av = 0.f;
      for (int d = 0; d < 64; ++d) {
        float u = u_attn[(h * 64 + d) * 32 + r];
        aq += qkv_b[h * 64 + d] * u;
        ak += qkv_b[1024 + h * 64 + d] * u;
        av += qkv_b[2048 + h * 64 + d] * u;
      }
      BQKV[h * 32 + r] = aq;
      BQKV[512 + h * 32 + r] = ak;
      BQKV[1024 + h * 32 + r] = av;
    }
  } else if (blk < 24) {
    int kb = (blk - 16) * 128;
    for (int i = tid; i < 4096; i += 256) {
      int r = i >> 7, kl = i & 127;
      UT[r * 1024 + kb + kl] = f2b(qkv_u[(kb + kl) * 32 + r]);
    }
  } else {
    int db = (blk - 24) * 128;
    for (int i = tid; i < 4096; i += 256) {
      int dl = i >> 5, r = i & 31;
      OVT[(db + dl) * 32 + r] = f2b(out_v[r * 1024 + db + dl]);
    }
  }
}

// ---------------------------------------------------------------------------
// K2: T = x @ qkv_u -> bf16 [8192][32]. MFMA, block = 32-row tile, 4 waves
// split K (256 each, 16 steps), LDS reduce.
// ---------------------------------------------------------------------------
__global__ __launch_bounds__(256) void k_proj(const float* __restrict__ x,
                                              const u16* __restrict__ UT,
                                              u16* __restrict__ T) {
  __shared__ float red[4][32][33];
  int tid = threadIdx.x;
  int w = tid >> 6, l = tid & 63, lo = l & 31, hi = l >> 5;
  int m0 = blockIdx.x * 32;
  const float* xp = x + (size_t)(m0 + lo) * 1024 + w * 256 + hi * 8;
  const u16* up = UT + lo * 1024 + w * 256 + hi * 8;
  f32x16 acc = {};
  for (int s = 0; s < 16; ++s) {
    float4 x0 = *(const float4*)(xp);
    float4 x1 = *(const float4*)(xp + 4);
    xp += 16;
    union { bf16x8 v; u32 u[4]; } af;
    af.u[0] = pk2(x0.x, x0.y);
    af.u[1] = pk2(x0.z, x0.w);
    af.u[2] = pk2(x1.x, x1.y);
    af.u[3] = pk2(x1.z, x1.w);
    bf16x8 bf = *(const bf16x8*)(up);
    up += 16;
    acc = MFMA(af.v, bf, acc, 0, 0, 0);
  }
#pragma unroll
  for (int i = 0; i < 16; ++i)
    red[w][(i & 3) + 8 * (i >> 2) + 4 * hi][lo] = acc[i];
  __syncthreads();
  int m = tid >> 3, c = (tid & 7) * 4;
  float v0 = red[0][m][c + 0] + red[1][m][c + 0] + red[2][m][c + 0] + red[3][m][c + 0];
  float v1 = red[0][m][c + 1] + red[1][m][c + 1] + red[2][m][c + 1] + red[3][m][c + 1];
  float v2 = red[0][m][c + 2] + red[1][m][c + 2] + red[2][m][c + 2] + red[3][m][c + 2];
  float v3 = red[0][m][c + 3] + red[1][m][c + 3] + red[2][m][c + 3] + red[3][m][c + 3];
  uint2 o;
  o.x = pk2(v0, v1);
  o.y = pk2(v2, v3);
  *(uint2*)(T + (size_t)(m0 + m) * 32 + c) = o;
}

// ---------------------------------------------------------------------------
// K3: per-head low-rank Q/K/V via MFMA. Wave = one 32-s tile; 6 MFMAs.
// QL/KL [bh][s][32] bf16 (Q scaled), VT [bh][32][s] via LDS transpose.
// ---------------------------------------------------------------------------
__global__ __launch_bounds__(256) void k_lowproj(const u16* __restrict__ T,
                                                 const u16* __restrict__ WQT,
                                                 const u16* __restrict__ WKT,
                                                 const u16* __restrict__ WVT,
                                                 const float* __restrict__ BQKV,
                                                 u16* __restrict__ QL, u16* __restrict__ KL,
                                                 u16* __restrict__ VT) {
  __shared__ u16 vt[32][136];
  int tid = threadIdx.x;
  int w = tid >> 6, l = tid & 63, lo = l & 31, hi = l >> 5;
  int blk = blockIdx.x;  // 64 bh * 16 sblocks
  int bh = blk >> 4, sb = (blk & 15) * 128;
  int b = bh >> 4, h = bh & 15;
  int s0 = sb + w * 32;

  const u16* wq = WQT + (h * 32 + lo) * 32 + hi * 8;
  const u16* wk = WKT + (h * 32 + lo) * 32 + hi * 8;
  const u16* wv = WVT + (h * 32 + lo) * 32 + hi * 8;
  bf16x8 aq0 = *(const bf16x8*)(wq), aq1 = *(const bf16x8*)(wq + 16);
  bf16x8 ak0 = *(const bf16x8*)(wk), ak1 = *(const bf16x8*)(wk + 16);
  bf16x8 av0 = *(const bf16x8*)(wv), av1 = *(const bf16x8*)(wv + 16);

  const u16* tp = T + (size_t)(b * 2048 + s0 + lo) * 32 + hi * 8;
  bf16x8 tb0 = *(const bf16x8*)(tp), tb1 = *(const bf16x8*)(tp + 16);

  f32x16 cq = {}, ck = {}, cv = {};
  cq = MFMA(aq0, tb0, cq, 0, 0, 0);
  cq = MFMA(aq1, tb1, cq, 0, 0, 0);
  ck = MFMA(ak0, tb0, ck, 0, 0, 0);
  ck = MFMA(ak1, tb1, ck, 0, 0, 0);
  cv = MFMA(av0, tb0, cv, 0, 0, 0);
  cv = MFMA(av1, tb1, cv, 0, 0, 0);

  size_t sg = (size_t)bh * 2048 + s0 + lo;
#pragma unroll
  for (int g2 = 0; g2 < 4; ++g2) {
    float4 bq4 = *(const float4*)(BQKV + h * 32 + g2 * 8 + 4 * hi);
    float4 bk4 = *(const float4*)(BQKV + 512 + h * 32 + g2 * 8 + 4 * hi);
    float4 bv4 = *(const float4*)(BQKV + 1024 + h * 32 + g2 * 8 + 4 * hi);
    float q0 = (cq[4 * g2 + 0] + bq4.x) * QSCALE;
    float q1 = (cq[4 * g2 + 1] + bq4.y) * QSCALE;
    float q2 = (cq[4 * g2 + 2] + bq4.z) * QSCALE;
    float q3 = (cq[4 * g2 + 3] + bq4.w) * QSCALE;
    uint2 qo; qo.x = pk2(q0, q1); qo.y = pk2(q2, q3);
    *(uint2*)(QL + sg * 32 + g2 * 8 + 4 * hi) = qo;
    float k0 = ck[4 * g2 + 0] + bk4.x, k1 = ck[4 * g2 + 1] + bk4.y;
    float k2 = ck[4 * g2 + 2] + bk4.z, k3 = ck[4 * g2 + 3] + bk4.w;
    uint2 ko; ko.x = pk2(k0, k1); ko.y = pk2(k2, k3);
    *(uint2*)(KL + sg * 32 + g2 * 8 + 4 * hi) = ko;
    int rbase = g2 * 8 + 4 * hi;
    int sl = w * 32 + lo;
    vt[rbase + 0][sl] = f2b(cv[4 * g2 + 0] + bv4.x);
    vt[rbase + 1][sl] = f2b(cv[4 * g2 + 1] + bv4.y);
    vt[rbase + 2][sl] = f2b(cv[4 * g2 + 2] + bv4.z);
    vt[rbase + 3][sl] = f2b(cv[4 * g2 + 3] + bv4.w);
  }
  __syncthreads();
  for (int u = tid; u < 512; u += 256) {
    int r = u >> 4, su = (u & 15) * 8;
    *(uint4*)(VT + ((size_t)bh * 32 + r) * 2048 + sb + su) = *(const uint4*)&vt[r][su];
  }
}

// ---------------------------------------------------------------------------
// K4: flash attention (swapped-operand 32x32x16 MFMA), defer-max online
// softmax, bf16 ctx out [b][s][h][r] via LDS transpose.
// ---------------------------------------------------------------------------
__global__ __launch_bounds__(256) void k_attn(const u16* __restrict__ QL,
                                              const u16* __restrict__ KL,
                                              const u16* __restrict__ VT,
                                              const int* __restrict__ mask,
                                              u16* __restrict__ CTX) {
  __shared__ u32 cls[128][17];
  int tid = threadIdx.x;
  int wave = tid >> 6, l = tid & 63, lo = l & 31, hi = l >> 5;
  int blk = blockIdx.x;
  int bh = blk >> 4;
  int qt = (blk & 15) * 4 + wave;
  int b = bh >> 4, h = bh & 15;

  const u16* QLbh = QL + (size_t)bh * 65536;
  const u16* KLbh = KL + (size_t)bh * 65536;
  const u16* VTbh = VT + (size_t)bh * 65536;
  const int* mk = mask + b * 2048;

  int q = qt * 32 + lo;
  bf16x8 qb0 = *(const bf16x8*)(QLbh + q * 32 + hi * 8);
  bf16x8 qb1 = *(const bf16x8*)(QLbh + q * 32 + 16 + hi * 8);

  f32x16 acc = {};
  float m_run = -1.0e30f, l_run = 0.f;

#pragma unroll 2
  for (int kt = 0; kt < 64; ++kt) {
    int kb = kt * 32;
    unsigned long long bm = __ballot(mk[kb + lo] != 0);
    const u16* kp = KLbh + (size_t)(kb + lo) * 32 + hi * 8;
    bf16x8 ka0 = *(const bf16x8*)(kp);
    bf16x8 ka1 = *(const bf16x8*)(kp + 16);
    f32x16 sc = {};
    sc = MFMA(ka0, qb0, sc, 0, 0, 0);
    sc = MFMA(ka1, qb1, sc, 0, 0, 0);
    if (~bm) {
      u32 km = (u32)bm;
#pragma unroll
      for (int i = 0; i < 16; ++i) {
        int key = (i & 3) + 8 * (i >> 2) + 4 * hi;
        if (!((km >> key) & 1)) sc[i] = -3.0e38f;
      }
    }
    // max over the 16 local scores (tree -> v_max3 fusion), then cross-half
    float a0 = fmaxf(sc[0], sc[1]), a1 = fmaxf(sc[2], sc[3]);
    float a2 = fmaxf(sc[4], sc[5]), a3 = fmaxf(sc[6], sc[7]);
    float a4 = fmaxf(sc[8], sc[9]), a5 = fmaxf(sc[10], sc[11]);
    float a6 = fmaxf(sc[12], sc[13]), a7 = fmaxf(sc[14], sc[15]);
    float mx = fmaxf(fmaxf(fmaxf(a0, a1), fmaxf(a2, a3)),
                     fmaxf(fmaxf(a4, a5), fmaxf(a6, a7)));
    mx = xhalf_max(mx);
    if (!__all(mx - m_run <= 8.0f)) {  // T13 defer-max
      float mn = fmaxf(m_run, mx);
      float alpha = __builtin_amdgcn_exp2f(m_run - mn);
      m_run = mn;
      l_run *= alpha;
#pragma unroll
      for (int i = 0; i < 16; ++i) acc[i] *= alpha;
    }
    float p[16];
    float ps = 0.f;
#pragma unroll
    for (int i = 0; i < 16; ++i) {
      p[i] = __builtin_amdgcn_exp2f(sc[i] - m_run);
      ps += p[i];
    }
    l_run += xhalf_sum(ps);
#pragma unroll
    for (int c = 0; c < 2; ++c) {
      u32 W0 = pk2(p[8 * c + 0], p[8 * c + 1]);
      u32 W1 = pk2(p[8 * c + 2], p[8 * c + 3]);
      u32 W2 = pk2(p[8 * c + 4], p[8 * c + 5]);
      u32 W3 = pk2(p[8 * c + 6], p[8 * c + 7]);
      u32 pW0 = __shfl_xor(W0, 32);
      u32 pW1 = __shfl_xor(W1, 32);
      u32 pW2 = __shfl_xor(W2, 32);
      u32 pW3 = __shfl_xor(W3, 32);
      union { bf16x8 v; u32 u[4]; } fb;
      fb.u[0] = hi ? pW2 : W0;
      fb.u[1] = hi ? pW3 : W1;
      fb.u[2] = hi ? W2 : pW0;
      fb.u[3] = hi ? W3 : pW1;
      bf16x8 va = *(const bf16x8*)(VTbh + (size_t)lo * 2048 + kb + c * 16 + hi * 8);
      acc = MFMA(va, fb.v, acc, 0, 0, 0);
    }
  }
  float inv = 1.0f / l_run;
  int qloc = wave * 32 + lo;
#pragma unroll
  for (int g2 = 0; g2 < 4; ++g2) {
    cls[qloc][g2 * 4 + 2 * hi] = pk2(acc[4 * g2 + 0] * inv, acc[4 * g2 + 1] * inv);
    cls[qloc][g2 * 4 + 2 * hi + 1] = pk2(acc[4 * g2 + 2] * inv, acc[4 * g2 + 3] * inv);
  }
  __syncthreads();
  int s_loc = tid >> 1, half = tid & 1;
  int srow = (blk & 15) * 128 + s_loc;
  const u32* src = &cls[s_loc][half * 8];
  uint4 v0, v1;
  v0.x = src[0]; v0.y = src[1]; v0.z = src[2]; v0.w = src[3];
  v1.x = src[4]; v1.y = src[5]; v1.z = src[6]; v1.w = src[7];
  u16* dst = CTX + (((size_t)(b * 2048 + srow)) * 16 + h) * 32 + half * 16;
  *(uint4*)(dst) = v0;
  *(uint4*)(dst + 8) = v1;
}

// ---------------------------------------------------------------------------
// K5a: ylow[s][r2] = ctx[s][0:512] @ WOT^T. Block = 32-row tile, 4-way K
// split, LDS reduce, bf16 out.
// ---------------------------------------------------------------------------
__global__ __launch_bounds__(256) void k_epi1(const u16* __restrict__ CTX,
                                              const u16* __restrict__ WOT,
                                              u16* __restrict__ YL) {
  __shared__ float red[4][32][33];
  int tid = threadIdx.x;
  int w = tid >> 6, l = tid & 63, lo = l & 31, hi = l >> 5;
  int s0 = blockIdx.x * 32;
  const u16* cp = CTX + (size_t)(s0 + lo) * 512 + w * 128 + hi * 8;
  const u16* wp = WOT + lo * 512 + w * 128 + hi * 8;
  f32x16 acc = {};
  for (int st = 0; st < 8; ++st) {
    bf16x8 a = *(const bf16x8*)(cp);
    bf16x8 bb = *(const bf16x8*)(wp);
    cp += 16;
    wp += 16;
    acc = MFMA(a, bb, acc, 0, 0, 0);
  }
#pragma unroll
  for (int i = 0; i < 16; ++i)
    red[w][(i & 3) + 8 * (i >> 2) + 4 * hi][lo] = acc[i];
  __syncthreads();
  int m = tid >> 3, c = (tid & 7) * 4;
  float v0 = red[0][m][c + 0] + red[1][m][c + 0] + red[2][m][c + 0] + red[3][m][c + 0];
  float v1 = red[0][m][c + 1] + red[1][m][c + 1] + red[2][m][c + 1] + red[3][m][c + 1];
  float v2 = red[0][m][c + 2] + red[1][m][c + 2] + red[2][m][c + 2] + red[3][m][c + 2];
  float v3 = red[0][m][c + 3] + red[1][m][c + 3] + red[2][m][c + 3] + red[3][m][c + 3];
  uint2 o;
  o.x = pk2(v0, v1);
  o.y = pk2(v2, v3);
  *(uint2*)(YL + (size_t)(s0 + m) * 32 + c) = o;
}

// ---------------------------------------------------------------------------
// K5b: out = ylow @ out_v + out_b. Block = 32 s x 128 d (4 waves, one d-sub
// tile each), LDS-staged coalesced f32 stores.
// ---------------------------------------------------------------------------
__global__ __launch_bounds__(256) void k_epi2(const u16* __restrict__ YL,
                                              const u16* __restrict__ OVT,
                                              const float* __restrict__ out_b,
                                              float* __restrict__ out) {
  __shared__ float ol[32][133];
  int tid = threadIdx.x;
  int w = tid >> 6, l = tid & 63, lo = l & 31, hi = l >> 5;
  int blk = blockIdx.x;  // 256 s-tiles x 8 d-tiles
  int s0 = (blk >> 3) * 32;
  int d0 = (blk & 7) * 128;
  int dw = d0 + w * 32;
  const u16* ap = OVT + (size_t)(dw + lo) * 32 + hi * 8;
  bf16x8 a0 = *(const bf16x8*)(ap), a1 = *(const bf16x8*)(ap + 16);
  const u16* bp = YL + (size_t)(s0 + lo) * 32 + hi * 8;
  bf16x8 b0 = *(const bf16x8*)(bp), b1 = *(const bf16x8*)(bp + 16);
  f32x16 acc = {};
  acc = MFMA(a0, b0, acc, 0, 0, 0);
  acc = MFMA(a1, b1, acc, 0, 0, 0);
#pragma unroll
  for (int i = 0; i < 16; ++i)
    ol[lo][w * 32 + (i & 3) + 8 * (i >> 2) + 4 * hi] = acc[i];
  __syncthreads();
  for (int u = tid; u < 1024; u += 256) {
    int s = u >> 5, c = (u & 31) * 4;
    float4 ob = *(const float4*)(out_b + d0 + c);
    float4 o;
    o.x = ol[s][c + 0] + ob.x;
    o.y = ol[s][c + 1] + ob.y;
    o.z = ol[s][c + 2] + ob.z;
    o.w = ol[s][c + 3] + ob.w;
    *(float4*)(out + (size_t)(s0 + s) * 1024 + d0 + c) = o;
  }
}

extern "C" void kernel_launch(void* const* d_in, const int* in_sizes, int n_in,
                              void* d_out, int out_size, void* d_ws, size_t ws_size,
                              hipStream_t stream) {
  const float* x = (const float*)d_in[0];
  const int* mask = (const int*)d_in[1];
  const float* qkv_u = (const float*)d_in[2];
  const float* qkv_v = (const float*)d_in[3];
  const float* qkv_b = (const float*)d_in[4];
  const float* u_attn = (const float*)d_in[5];
  const float* v_attn = (const float*)d_in[6];
  const float* out_u = (const float*)d_in[7];
  const float* out_v = (const float*)d_in[8];
  const float* out_b = (const float*)d_in[9];
  float* out = (float*)d_out;

  char* w = (char*)d_ws;
  u16* WQT = (u16*)(w + 0);                // 32 KB
  u16* WKT = (u16*)(w + (32 << 10));       // 32 KB
  u16* WVT = (u16*)(w + (64 << 10));       // 32 KB
  float* BQ = (float*)(w + (96 << 10));    // 6 KB
  u16* WOT = (u16*)(w + (104 << 10));      // 32 KB
  u16* UT = (u16*)(w + (136 << 10));       // 64 KB
  u16* OVT = (u16*)(w + (200 << 10));      // 64 KB
  u16* T = (u16*)(w + (1 << 20));          // 512 KB bf16 [8192][32]
  u16* QL = (u16*)(w + (2 << 20));         // 8 MB bf16 [bh][s][32]
  u16* KL = (u16*)(w + (10 << 20));        // 8 MB bf16 [bh][s][32]
  u16* VT = (u16*)(w + (18 << 20));        // 8 MB bf16 [bh][32][s]
  u16* CTX = (u16*)(w + (26 << 20));       // 8 MB bf16 [8192][512]
  u16* YL = (u16*)(w + (34 << 20));        // 512 KB bf16 [8192][32]

  k_prep<<<32, 256, 0, stream>>>(qkv_v, qkv_b, u_attn, v_attn, out_u, qkv_u, out_v,
                                 WQT, WKT, WVT, BQ, WOT, UT, OVT);
  k_proj<<<256, 256, 0, stream>>>(x, UT, T);
  k_lowproj<<<1024, 256, 0, stream>>>(T, WQT, WKT, WVT, BQ, QL, KL, VT);
  k_attn<<<1024, 256, 0, stream>>>(QL, KL, VT, mask, CTX);
  k_epi1<<<256, 256, 0, stream>>>(CTX, WOT, YL);
  k_epi2<<<2048, 256, 0, stream>>>(YL, OVT, out_b, out);
}